// Round 5
// baseline (7319.598 us; speedup 1.0000x reference)
//
#include <hip/hip_runtime.h>
#include <hip/hip_bf16.h>

#define SEQ 2048
#define DM  512
#define NH  8
#define DH  64

// ---------- N1: per-head projections (pure f32 VALU) ----------
// grid: (M*64/256 = 2048, H, 3), block 256. Thread -> (m, o) for tensor z, head h.
// out layout [B,H,SEQ,DH] f32.
__global__ __launch_bounds__(256) void proj_naive(const float* __restrict__ q,
                                                  const float* __restrict__ k,
                                                  const float* __restrict__ v,
                                                  const float* __restrict__ Wq,
                                                  const float* __restrict__ Wk,
                                                  const float* __restrict__ Wv,
                                                  const float* __restrict__ bq,
                                                  const float* __restrict__ bk,
                                                  const float* __restrict__ bv,
                                                  float* __restrict__ Qp,
                                                  float* __restrict__ Kp,
                                                  float* __restrict__ Vp) {
  const int which = blockIdx.z;
  const float* X  = (which == 0) ? q  : (which == 1) ? k  : v;
  const float* W  = (which == 0) ? Wq : (which == 1) ? Wk : Wv;
  const float* bb = (which == 0) ? bq : (which == 1) ? bk : bv;
  float* O        = (which == 0) ? Qp : (which == 1) ? Kp : Vp;
  const int h = blockIdx.y;
  const int idx = blockIdx.x * 256 + threadIdx.x;  // m*64 + o
  const int m = idx >> 6, o = idx & 63;
  const float* xr = X + (size_t)m * DM;
  const float* wh = W + (size_t)h * DM * DH;       // W[h][d][o]
  float acc = bb[h * DH + o];
  for (int d = 0; d < DM; ++d)
    acc = fmaf(xr[d], wh[d * DH + o], acc);
  const int b = m >> 11, s = m & (SEQ - 1);
  O[(((size_t)(b * NH + h) * SEQ) + s) * DH + o] = acc;
}

// ---------- N2: causal attention, one block per (bh, query row) ----------
// grid (SEQ, B*NH), block 256. concat [B,SEQ,DM] f32.
__global__ __launch_bounds__(256) void attn_naive(const float* __restrict__ Qp,
                                                  const float* __restrict__ Kp,
                                                  const float* __restrict__ Vp,
                                                  float* __restrict__ concat) {
  const int kq = blockIdx.x;
  const int bh = blockIdx.y;
  const int b = bh >> 3, h = bh & 7;
  const float* qr = Qp + ((size_t)bh * SEQ + kq) * DH;
  const float* Kb = Kp + (size_t)bh * SEQ * DH;
  const float* Vb = Vp + (size_t)bh * SEQ * DH;
  __shared__ float s[SEQ];
  __shared__ float qs[DH];
  __shared__ float red[256];
  const int tid = threadIdx.x;
  const float scale = 0.022097086912079608f;  // 1/sqrt(2048)

  if (tid < DH) qs[tid] = qr[tid];
  __syncthreads();

  // scores s[l] = (q . k_l) * scale, l in [0, kq]
  for (int l = tid; l <= kq; l += 256) {
    const float* kr = Kb + (size_t)l * DH;
    float acc = 0.f;
#pragma unroll
    for (int d = 0; d < DH; ++d) acc = fmaf(qs[d], kr[d], acc);
    s[l] = acc * scale;
  }
  __syncthreads();

  // row max
  float mx = -INFINITY;
  for (int l = tid; l <= kq; l += 256) mx = fmaxf(mx, s[l]);
  red[tid] = mx;
  __syncthreads();
  for (int w = 128; w >= 1; w >>= 1) {
    if (tid < w) red[tid] = fmaxf(red[tid], red[tid + w]);
    __syncthreads();
  }
  mx = red[0];
  __syncthreads();

  // p = exp(s - mx), partial sums
  float sm = 0.f;
  for (int l = tid; l <= kq; l += 256) {
    float p = __expf(s[l] - mx);
    s[l] = p;
    sm += p;
  }
  red[tid] = sm;
  __syncthreads();
  for (int w = 128; w >= 1; w >>= 1) {
    if (tid < w) red[tid] += red[tid + w];
    __syncthreads();
  }
  const float denom = red[0];
  __syncthreads();

  // O[o] = sum_l p_l * V[l][o]; 4 l-strided groups of 64 lanes, then LDS combine
  const int o = tid & 63, g = tid >> 6;
  float acc = 0.f;
  for (int l = g; l <= kq; l += 4) acc = fmaf(s[l], Vb[(size_t)l * DH + o], acc);
  red[tid] = acc;
  __syncthreads();
  if (tid < 64) {
    float tot = red[tid] + red[tid + 64] + red[tid + 128] + red[tid + 192];
    concat[((size_t)(b * SEQ + kq)) * DM + h * DH + tid] = tot / denom;
  }
}

// ---------- N3: output projection (pure f32 VALU), write FLOAT32 ----------
// grid: M*DM/256 = 16384, block 256. Thread -> (m, d).
__global__ __launch_bounds__(256) void outproj_naive(const float* __restrict__ concat,
                                                     const float* __restrict__ Wo,
                                                     const float* __restrict__ bo,
                                                     float* __restrict__ out) {
  const size_t idx = (size_t)blockIdx.x * 256 + threadIdx.x;  // m*512 + d
  const int m = (int)(idx >> 9), d = (int)(idx & 511);
  const float* cr = concat + (size_t)m * DM;
  float acc = bo[d];
  for (int j = 0; j < DM; ++j)
    acc = fmaf(cr[j], Wo[(size_t)j * DM + d], acc);
  out[idx] = acc;
}

extern "C" void kernel_launch(void* const* d_in, const int* in_sizes, int n_in,
                              void* d_out, int out_size, void* d_ws, size_t ws_size,
                              hipStream_t stream) {
  const float* query = (const float*)d_in[0];
  const float* key   = (const float*)d_in[1];
  const float* value = (const float*)d_in[2];
  const float* W_q   = (const float*)d_in[3];
  const float* b_q   = (const float*)d_in[4];
  const float* W_k   = (const float*)d_in[5];
  const float* b_k   = (const float*)d_in[6];
  const float* W_v   = (const float*)d_in[7];
  const float* b_v   = (const float*)d_in[8];
  const float* W_o   = (const float*)d_in[9];
  const float* b_o   = (const float*)d_in[10];
  float* out = (float*)d_out;

  char* ws = (char*)d_ws;
  float* Qp     = (float*)(ws + 0);                    // [B,H,S,64] f32 = 16 MB
  float* Kp     = (float*)(ws + (size_t)16777216);     // 16 MB
  float* Vp     = (float*)(ws + (size_t)33554432);     // 16 MB
  float* concat = (float*)(ws + (size_t)50331648);     // [B,S,512] f32 = 16 MB
  // total ws use: 64 MB

  proj_naive<<<dim3(2048, NH, 3), 256, 0, stream>>>(query, key, value,
                                                    W_q, W_k, W_v,
                                                    b_q, b_k, b_v,
                                                    Qp, Kp, Vp);

  attn_naive<<<dim3(SEQ, 4 * NH), 256, 0, stream>>>(Qp, Kp, Vp, concat);

  outproj_naive<<<dim3(16384), 256, 0, stream>>>(concat, W_o, b_o, out);
}

// Round 6
// 283.278 us; speedup vs baseline: 25.8389x; 25.8389x over previous
//
#include <hip/hip_runtime.h>
#include <hip/hip_bf16.h>

typedef __attribute__((ext_vector_type(8))) short bf16x8;
typedef __attribute__((ext_vector_type(4))) float f32x4;

#define SEQ 2048
#define DM  512
#define NH  8
#define DH  64

__device__ __forceinline__ float bf2f(unsigned short u) {
  return __uint_as_float(((unsigned int)u) << 16);
}
__device__ __forceinline__ unsigned short f2bf(float f) {
  unsigned int u = __float_as_uint(f);
  unsigned int r = 0x7FFFu + ((u >> 16) & 1u);
  return (unsigned short)((u + r) >> 16);
}

// load 8 contiguous f32 elements, convert to bf16
__device__ __forceinline__ void load8f(const float* __restrict__ s,
                                       unsigned short* __restrict__ o) {
  float4 v0 = *(const float4*)s;
  float4 v1 = *(const float4*)(s + 4);
  o[0] = f2bf(v0.x); o[1] = f2bf(v0.y); o[2] = f2bf(v0.z); o[3] = f2bf(v0.w);
  o[4] = f2bf(v1.x); o[5] = f2bf(v1.y); o[6] = f2bf(v1.z); o[7] = f2bf(v1.w);
}

// ---------- f32 -> bf16 batched 64x64 transpose: dst[c][r] = bf16(src[r][c]) ----------
__global__ __launch_bounds__(256) void transpose_w(const float* __restrict__ src,
                                                   unsigned short* __restrict__ dst,
                                                   int R, int C) {
  const size_t bs = (size_t)R * C;
  src += (size_t)blockIdx.z * bs;
  dst += (size_t)blockIdx.z * bs;
  const int r0 = blockIdx.y * 64, c0 = blockIdx.x * 64;
  __shared__ __align__(16) unsigned short T[64][72];
  const int tid = threadIdx.x;
#pragma unroll
  for (int i = 0; i < 2; ++i) {
    int c = tid + 256 * i;
    int lr = c >> 3, lc = (c & 7) * 8;
    __align__(16) unsigned short tmp[8];
    load8f(src + (size_t)(r0 + lr) * C + c0 + lc, tmp);
    *(uint4*)&T[lr][lc] = *(const uint4*)tmp;
  }
  __syncthreads();
#pragma unroll
  for (int i = 0; i < 2; ++i) {
    int c = tid + 256 * i;
    int orow = c >> 3, och = (c & 7) * 8;
    __align__(16) unsigned short tmp[8];
#pragma unroll
    for (int j = 0; j < 8; ++j) tmp[j] = T[och + j][orow];
    *(uint4*)(dst + (size_t)(c0 + orow) * R + r0 + och) = *(uint4*)tmp;
  }
}

// ---------- projections: C = bf16(A_f32)[M,KD] @ Bt^T + bias ----------
// mode 0: out [B,H,SEQ,DH] (h = blockIdx.y);  mode 2: out [B,H,DH,SEQ] (V^T)
__global__ __launch_bounds__(256) void gemm_bt(const float* __restrict__ A,
                                               const unsigned short* __restrict__ Bt,
                                               const float* __restrict__ bias,
                                               unsigned short* __restrict__ out,
                                               int KD, int mode) {
  const int m0 = blockIdx.x * 64;
  const int n0 = blockIdx.y * 64;
  __shared__ __align__(16) unsigned short As[64][72];
  __shared__ __align__(16) unsigned short Bs[64][72];
  const int tid  = threadIdx.x;
  const int wave = tid >> 6, lane = tid & 63;
  const int l15  = lane & 15, quad = lane >> 4;
  f32x4 acc[4];
#pragma unroll
  for (int f = 0; f < 4; ++f) acc[f] = (f32x4){0.f, 0.f, 0.f, 0.f};

  for (int k0 = 0; k0 < KD; k0 += 64) {
    __syncthreads();
#pragma unroll
    for (int i = 0; i < 2; ++i) {
      int c = tid + 256 * i;
      int lr = c >> 3, lc = (c & 7) * 8;
      __align__(16) unsigned short tmp[8];
      load8f(A + (size_t)(m0 + lr) * KD + k0 + lc, tmp);
      *(uint4*)&As[lr][lc] = *(const uint4*)tmp;
      *(uint4*)&Bs[lr][lc] = *(const uint4*)(Bt + (size_t)(n0 + lr) * KD + k0 + lc);
    }
    __syncthreads();
#pragma unroll
    for (int kc = 0; kc < 2; ++kc) {
      bf16x8 af = *(const bf16x8*)&As[16 * wave + l15][kc * 32 + quad * 8];
#pragma unroll
      for (int f = 0; f < 4; ++f) {
        bf16x8 bfv = *(const bf16x8*)&Bs[16 * f + l15][kc * 32 + quad * 8];
        acc[f] = __builtin_amdgcn_mfma_f32_16x16x32_bf16(af, bfv, acc[f], 0, 0, 0);
      }
    }
  }
  const int bb = m0 >> 11, kk0 = m0 & (SEQ - 1);
  if (mode == 0) {
#pragma unroll
    for (int f = 0; f < 4; ++f)
#pragma unroll
      for (int r = 0; r < 4; ++r) {
        int row = 16 * wave + quad * 4 + r;
        int col = 16 * f + l15;
        float v = acc[f][r] + bias[n0 + col];
        out[(((size_t)(bb * NH + blockIdx.y) * SEQ + kk0 + row) << 6) + col] = f2bf(v);
      }
  } else {  // mode 2: V^T via LDS bounce, coalesced store along SEQ
    __syncthreads();
#pragma unroll
    for (int f = 0; f < 4; ++f)
#pragma unroll
      for (int r = 0; r < 4; ++r) {
        int row = 16 * wave + quad * 4 + r;   // seq-local
        int col = 16 * f + l15;               // dh
        As[col][row] = f2bf(acc[f][r] + bias[n0 + col]);
      }
    __syncthreads();
#pragma unroll
    for (int i = 0; i < 2; ++i) {
      int c = tid + 256 * i;
      int lr = c >> 3, lc = (c & 7) * 8;      // lr = dh, lc = seq-offset
      *(uint4*)(out + ((size_t)(bb * NH + blockIdx.y) * DH + lr) * SEQ + kk0 + lc) =
          *(const uint4*)&As[lr][lc];
    }
  }
}

// ---------- flash attention (quad-shfl softmax) -> concat bf16 [B,SEQ,DM] ----------
__global__ __launch_bounds__(256) void attn_kernel(const unsigned short* __restrict__ Qp,
                                                   const unsigned short* __restrict__ Kp,
                                                   const unsigned short* __restrict__ Vpt,
                                                   unsigned short* __restrict__ concat) {
  const int bh = blockIdx.y;
  const int xb = blockIdx.x;
  const int b = bh >> 3, h = bh & 7;
  __shared__ __align__(16) unsigned short Qs[64][72], Ks[64][72], Vts[64][72], Ps[64][72];
  const int tid  = threadIdx.x;
  const int wave = tid >> 6, lane = tid & 63;
  const int l15  = lane & 15, quad = lane >> 4;
  const unsigned short* Qb = Qp  + (size_t)bh * SEQ * DH;
  const unsigned short* Kb = Kp  + (size_t)bh * SEQ * DH;
  const unsigned short* Vb = Vpt + (size_t)bh * DH * SEQ;
  const float scale = 0.022097086912079608f;  // 1/sqrt(2048)

#pragma unroll 1
  for (int rep = 0; rep < 2; ++rep) {
    const int qt = rep ? (31 - xb) : xb;   // pair (x, 31-x): 33 key-tiles/block, balanced
    const int q0 = qt * 64;
    __syncthreads();
#pragma unroll
    for (int i = 0; i < 2; ++i) {
      int c = tid + 256 * i;
      int lr = c >> 3, lc = (c & 7) * 8;
      *(uint4*)&Qs[lr][lc] = *(const uint4*)(Qb + (size_t)(q0 + lr) * DH + lc);
    }
    float m_i[4], l_i[4];
    f32x4 Of[4];
#pragma unroll
    for (int r = 0; r < 4; ++r) { m_i[r] = -INFINITY; l_i[r] = 0.f; }
#pragma unroll
    for (int f = 0; f < 4; ++f) Of[f] = (f32x4){0.f, 0.f, 0.f, 0.f};
    __syncthreads();

#pragma unroll 1
    for (int lt = 0; lt <= qt; ++lt) {
      const int l0 = lt * 64;
      __syncthreads();
#pragma unroll
      for (int i = 0; i < 2; ++i) {
        int c = tid + 256 * i;
        int lr = c >> 3, lc = (c & 7) * 8;
        *(uint4*)&Ks[lr][lc]  = *(const uint4*)(Kb + (size_t)(l0 + lr) * DH + lc);
        *(uint4*)&Vts[lr][lc] = *(const uint4*)(Vb + (size_t)lr * SEQ + l0 + lc);
      }
      __syncthreads();

      // S = Q K^T
      f32x4 S[4];
#pragma unroll
      for (int f = 0; f < 4; ++f) S[f] = (f32x4){0.f, 0.f, 0.f, 0.f};
#pragma unroll
      for (int kc = 0; kc < 2; ++kc) {
        bf16x8 aq = *(const bf16x8*)&Qs[16 * wave + l15][kc * 32 + quad * 8];
#pragma unroll
        for (int f = 0; f < 4; ++f) {
          bf16x8 bk = *(const bf16x8*)&Ks[16 * f + l15][kc * 32 + quad * 8];
          S[f] = __builtin_amdgcn_mfma_f32_16x16x32_bf16(aq, bk, S[f], 0, 0, 0);
        }
      }
      const int mrow = q0 + 16 * wave + quad * 4;  // + r
      if (lt == qt) {
#pragma unroll
        for (int f = 0; f < 4; ++f)
#pragma unroll
          for (int r = 0; r < 4; ++r) {
            float s = S[f][r] * scale;
            if (l0 + 16 * f + l15 > mrow + r) s = -INFINITY;
            S[f][r] = s;
          }
      } else {
#pragma unroll
        for (int f = 0; f < 4; ++f)
#pragma unroll
          for (int r = 0; r < 4; ++r) S[f][r] *= scale;
      }
      // row r lives across the 16 lanes sharing this quad -> shfl_xor 1/2/4/8
      float mx[4];
#pragma unroll
      for (int r = 0; r < 4; ++r)
        mx[r] = fmaxf(fmaxf(S[0][r], S[1][r]), fmaxf(S[2][r], S[3][r]));
#pragma unroll
      for (int d = 1; d < 16; d <<= 1)
#pragma unroll
        for (int r = 0; r < 4; ++r) mx[r] = fmaxf(mx[r], __shfl_xor(mx[r], d));

      float alpha[4], rs[4];
#pragma unroll
      for (int r = 0; r < 4; ++r) {
        float mnew = fmaxf(m_i[r], mx[r]);
        alpha[r] = __expf(m_i[r] - mnew);
        m_i[r] = mnew;
        rs[r] = 0.f;
      }
#pragma unroll
      for (int f = 0; f < 4; ++f)
#pragma unroll
        for (int r = 0; r < 4; ++r) {
          float p = __expf(S[f][r] - m_i[r]);
          rs[r] += p;
          Ps[16 * wave + quad * 4 + r][16 * f + l15] = f2bf(p);  // wave-private rows
        }
#pragma unroll
      for (int d = 1; d < 16; d <<= 1)
#pragma unroll
        for (int r = 0; r < 4; ++r) rs[r] += __shfl_xor(rs[r], d);
#pragma unroll
      for (int r = 0; r < 4; ++r) l_i[r] = l_i[r] * alpha[r] + rs[r];
#pragma unroll
      for (int f = 0; f < 4; ++f)
#pragma unroll
        for (int r = 0; r < 4; ++r) Of[f][r] *= alpha[r];

      // O += P @ V
#pragma unroll
      for (int kc = 0; kc < 2; ++kc) {
        bf16x8 ap = *(const bf16x8*)&Ps[16 * wave + l15][kc * 32 + quad * 8];
#pragma unroll
        for (int f = 0; f < 4; ++f) {
          bf16x8 bv = *(const bf16x8*)&Vts[16 * f + l15][kc * 32 + quad * 8];
          Of[f] = __builtin_amdgcn_mfma_f32_16x16x32_bf16(ap, bv, Of[f], 0, 0, 0);
        }
      }
    }

#pragma unroll
    for (int f = 0; f < 4; ++f)
#pragma unroll
      for (int r = 0; r < 4; ++r) {
        int row = 16 * wave + quad * 4 + r;
        float o = Of[f][r] / l_i[r];
        int col = h * DH + 16 * f + l15;
        concat[(size_t)(b * SEQ + q0 + row) * DM + col] = f2bf(o);
      }
  }
}

// ---------- output projection: out_f32 = concat_bf16 @ Wot^T + b_o ----------
__global__ __launch_bounds__(256) void gemm_out(const unsigned short* __restrict__ A,
                                                const unsigned short* __restrict__ Bt,
                                                const float* __restrict__ bias,
                                                float* __restrict__ out) {
  const int m0 = blockIdx.x * 64;
  __shared__ __align__(16) unsigned short Bs[64][72];
  const int tid  = threadIdx.x;
  const int wave = tid >> 6, lane = tid & 63;
  const int l15  = lane & 15, quad = lane >> 4;

  bf16x8 afr[16];  // per-wave A rows held in registers across all n0 tiles
  const unsigned short* arow = A + (size_t)(m0 + 16 * wave + l15) * DM;
#pragma unroll
  for (int k0i = 0; k0i < 8; ++k0i)
#pragma unroll
    for (int kc = 0; kc < 2; ++kc)
      afr[k0i * 2 + kc] = *(const bf16x8*)(arow + k0i * 64 + kc * 32 + quad * 8);

  for (int n0 = 0; n0 < DM; n0 += 64) {
    f32x4 acc[4];
#pragma unroll
    for (int f = 0; f < 4; ++f) acc[f] = (f32x4){0.f, 0.f, 0.f, 0.f};
    for (int k0i = 0; k0i < 8; ++k0i) {
      __syncthreads();
#pragma unroll
      for (int i = 0; i < 2; ++i) {
        int c = tid + 256 * i;
        int lr = c >> 3, lc = (c & 7) * 8;
        *(uint4*)&Bs[lr][lc] = *(const uint4*)(Bt + (size_t)(n0 + lr) * DM + k0i * 64 + lc);
      }
      __syncthreads();
#pragma unroll
      for (int kc = 0; kc < 2; ++kc) {
#pragma unroll
        for (int f = 0; f < 4; ++f) {
          bf16x8 bfv = *(const bf16x8*)&Bs[16 * f + l15][kc * 32 + quad * 8];
          acc[f] = __builtin_amdgcn_mfma_f32_16x16x32_bf16(afr[k0i * 2 + kc], bfv, acc[f], 0, 0, 0);
        }
      }
    }
#pragma unroll
    for (int f = 0; f < 4; ++f)
#pragma unroll
      for (int r = 0; r < 4; ++r) {
        int row = 16 * wave + quad * 4 + r;
        int col = 16 * f + l15;
        out[(size_t)(m0 + row) * DM + n0 + col] = acc[f][r] + bias[n0 + col];
      }
  }
}

extern "C" void kernel_launch(void* const* d_in, const int* in_sizes, int n_in,
                              void* d_out, int out_size, void* d_ws, size_t ws_size,
                              hipStream_t stream) {
  const float* query = (const float*)d_in[0];
  const float* key   = (const float*)d_in[1];
  const float* value = (const float*)d_in[2];
  const float* W_q   = (const float*)d_in[3];
  const float* b_q   = (const float*)d_in[4];
  const float* W_k   = (const float*)d_in[5];
  const float* b_k   = (const float*)d_in[6];
  const float* W_v   = (const float*)d_in[7];
  const float* b_v   = (const float*)d_in[8];
  const float* W_o   = (const float*)d_in[9];
  const float* b_o   = (const float*)d_in[10];
  float* out = (float*)d_out;

  char* ws = (char*)d_ws;
  unsigned short* Wqt    = (unsigned short*)(ws + 0);         // [H][64][512] bf16
  unsigned short* Wkt    = (unsigned short*)(ws + 524288);
  unsigned short* Wvt    = (unsigned short*)(ws + 1048576);
  unsigned short* Wot    = (unsigned short*)(ws + 1572864);   // [512][512] bf16
  unsigned short* Qp     = (unsigned short*)(ws + 2097152);   // [B,H,S,64] bf16 8 MB
  unsigned short* Kp     = (unsigned short*)(ws + 10485760);
  unsigned short* Vpt    = (unsigned short*)(ws + 18874368);  // [B,H,64,S] bf16 8 MB
  unsigned short* concat = (unsigned short*)(ws + 27262976);  // [B,S,512] bf16 8 MB
  // total ws use: ~33.6 MB (64 MB verified safe in round 5)

  transpose_w<<<dim3(1, 8, NH), 256, 0, stream>>>(W_q, Wqt, 512, 64);
  transpose_w<<<dim3(1, 8, NH), 256, 0, stream>>>(W_k, Wkt, 512, 64);
  transpose_w<<<dim3(1, 8, NH), 256, 0, stream>>>(W_v, Wvt, 512, 64);
  transpose_w<<<dim3(8, 8, 1), 256, 0, stream>>>(W_o, Wot, 512, 512);

  gemm_bt<<<dim3(128, 8), 256, 0, stream>>>(query, Wqt, b_q, Qp,  512, 0);
  gemm_bt<<<dim3(128, 8), 256, 0, stream>>>(key,   Wkt, b_k, Kp,  512, 0);
  gemm_bt<<<dim3(128, 8), 256, 0, stream>>>(value, Wvt, b_v, Vpt, 512, 2);

  attn_kernel<<<dim3(16, 32), 256, 0, stream>>>(Qp, Kp, Vpt, concat);

  gemm_out<<<dim3(128), 256, 0, stream>>>(concat, Wot, b_o, out);
}

// Round 7
// 234.905 us; speedup vs baseline: 31.1598x; 1.2059x over previous
//
#include <hip/hip_runtime.h>
#include <hip/hip_bf16.h>

typedef __attribute__((ext_vector_type(8))) short bf16x8;
typedef __attribute__((ext_vector_type(4))) float f32x4;

#define SEQ 2048
#define DM  512
#define NH  8
#define DH  64
// (1/sqrt(2048)) * log2(e): folded into Q so scores come out ready for exp2
#define QSCALE 0.031879360f

__device__ __forceinline__ unsigned short f2bf(float f) {
  unsigned int u = __float_as_uint(f);
  unsigned int r = 0x7FFFu + ((u >> 16) & 1u);
  return (unsigned short)((u + r) >> 16);
}

// load 8 contiguous f32, convert to bf16
__device__ __forceinline__ void load8f(const float* __restrict__ s,
                                       unsigned short* __restrict__ o) {
  float4 v0 = *(const float4*)s;
  float4 v1 = *(const float4*)(s + 4);
  o[0] = f2bf(v0.x); o[1] = f2bf(v0.y); o[2] = f2bf(v0.z); o[3] = f2bf(v0.w);
  o[4] = f2bf(v1.x); o[5] = f2bf(v1.y); o[6] = f2bf(v1.z); o[7] = f2bf(v1.w);
}

// ---------- fused weight prep: Wq/Wk/Wv per-head transpose + Wo transpose (f32->bf16) ----------
// 256 blocks: [0,64) Wq, [64,128) Wk, [128,192) Wv, [192,256) Wo
__global__ __launch_bounds__(256) void weight_prep(const float* __restrict__ Wq,
                                                   const float* __restrict__ Wk,
                                                   const float* __restrict__ Wv,
                                                   const float* __restrict__ Wo,
                                                   unsigned short* __restrict__ Wqt,
                                                   unsigned short* __restrict__ Wkt,
                                                   unsigned short* __restrict__ Wvt,
                                                   unsigned short* __restrict__ Wot) {
  const int which = blockIdx.x >> 6, wi = blockIdx.x & 63;
  const float* src;
  unsigned short* dst;
  int R, C, r0, c0;
  if (which < 3) {
    const float* W = (which == 0) ? Wq : (which == 1) ? Wk : Wv;
    unsigned short* D = (which == 0) ? Wqt : (which == 1) ? Wkt : Wvt;
    int h = wi >> 3;
    src = W + (size_t)h * 512 * 64;
    dst = D + (size_t)h * 64 * 512;
    R = 512; C = 64; r0 = (wi & 7) * 64; c0 = 0;
  } else {
    src = Wo; dst = Wot;
    R = 512; C = 512; r0 = (wi >> 3) * 64; c0 = (wi & 7) * 64;
  }
  __shared__ __align__(16) unsigned short T[64][72];
  const int tid = threadIdx.x;
#pragma unroll
  for (int i = 0; i < 2; ++i) {
    int c = tid + 256 * i;
    int lr = c >> 3, lc = (c & 7) * 8;
    __align__(16) unsigned short tmp[8];
    load8f(src + (size_t)(r0 + lr) * C + c0 + lc, tmp);
    *(uint4*)&T[lr][lc] = *(const uint4*)tmp;
  }
  __syncthreads();
#pragma unroll
  for (int i = 0; i < 2; ++i) {
    int c = tid + 256 * i;
    int orow = c >> 3, och = (c & 7) * 8;
    __align__(16) unsigned short tmp[8];
#pragma unroll
    for (int j = 0; j < 8; ++j) tmp[j] = T[och + j][orow];
    *(uint4*)(dst + (size_t)(c0 + orow) * R + r0 + och) = *(uint4*)tmp;
  }
}

// ---------- fused QKV projection, 128x128 tiles ----------
// z=0: Q (pre-scaled by QSCALE) -> Qp [B,H,S,64]; z=1: K -> Kp; z=2: V -> Vpt [B,H,64,S]
__global__ __launch_bounds__(256, 4) void proj128(const float* __restrict__ q,
                                                  const float* __restrict__ k,
                                                  const float* __restrict__ v,
                                                  const unsigned short* __restrict__ Wqt,
                                                  const unsigned short* __restrict__ Wkt,
                                                  const unsigned short* __restrict__ Wvt,
                                                  const float* __restrict__ bq,
                                                  const float* __restrict__ bk,
                                                  const float* __restrict__ bv,
                                                  unsigned short* __restrict__ Qp,
                                                  unsigned short* __restrict__ Kp,
                                                  unsigned short* __restrict__ Vpt) {
  const int which = blockIdx.z;
  const float* X = (which == 0) ? q : (which == 1) ? k : v;
  const unsigned short* Wt = (which == 0) ? Wqt : (which == 1) ? Wkt : Wvt;  // [512n][512k]
  const float* bias = (which == 0) ? bq : (which == 1) ? bk : bv;
  unsigned short* out = (which == 0) ? Qp : (which == 1) ? Kp : Vpt;
  const float ps = (which == 0) ? QSCALE : 1.0f;

  const int m0 = blockIdx.x * 128;
  const int n0 = blockIdx.y * 128;
  __shared__ __align__(16) unsigned short smem[2][128][72];
  unsigned short (*As)[72] = smem[0];
  unsigned short (*Bs)[72] = smem[1];
  const int tid  = threadIdx.x;
  const int wave = tid >> 6, lane = tid & 63;
  const int l15  = lane & 15, quad = lane >> 4;
  const int rb = (wave >> 1) * 64, cb = (wave & 1) * 64;

  f32x4 acc[4][4];
#pragma unroll
  for (int i = 0; i < 4; ++i)
#pragma unroll
    for (int f = 0; f < 4; ++f) acc[i][f] = (f32x4){0.f, 0.f, 0.f, 0.f};

  for (int k0 = 0; k0 < DM; k0 += 64) {
    __syncthreads();
#pragma unroll
    for (int i = 0; i < 4; ++i) {
      int c = tid + 256 * i;             // 1024 slots x 8 elems = 128x64
      int lr = c >> 3, lc = (c & 7) * 8;
      __align__(16) unsigned short tmp[8];
      load8f(X + (size_t)(m0 + lr) * DM + k0 + lc, tmp);
      *(uint4*)&As[lr][lc] = *(const uint4*)tmp;
      *(uint4*)&Bs[lr][lc] = *(const uint4*)(Wt + (size_t)(n0 + lr) * DM + k0 + lc);
    }
    __syncthreads();
#pragma unroll
    for (int kc = 0; kc < 2; ++kc) {
      bf16x8 av[4], bv4[4];
#pragma unroll
      for (int i = 0; i < 4; ++i) av[i]  = *(const bf16x8*)&As[rb + 16 * i + l15][kc * 32 + quad * 8];
#pragma unroll
      for (int f = 0; f < 4; ++f) bv4[f] = *(const bf16x8*)&Bs[cb + 16 * f + l15][kc * 32 + quad * 8];
#pragma unroll
      for (int i = 0; i < 4; ++i)
#pragma unroll
        for (int f = 0; f < 4; ++f)
          acc[i][f] = __builtin_amdgcn_mfma_f32_16x16x32_bf16(av[i], bv4[f], acc[i][f], 0, 0, 0);
    }
  }

  if (which < 2) {  // Q/K: [B,H,S,64]
#pragma unroll
    for (int i = 0; i < 4; ++i)
#pragma unroll
      for (int f = 0; f < 4; ++f)
#pragma unroll
        for (int r = 0; r < 4; ++r) {
          int m = m0 + rb + 16 * i + quad * 4 + r;
          int col = n0 + cb + 16 * f + l15;
          int head = col >> 6, o = col & 63;
          int b = m >> 11, s = m & (SEQ - 1);
          float val = (acc[i][f][r] + bias[col]) * ps;
          out[(((size_t)(b * NH + head) * SEQ + s) << 6) + o] = f2bf(val);
        }
  } else {  // V: emit V^T [B,H,64,S] via per-wave LDS bounce transpose
    __syncthreads();  // all waves done reading As/Bs
    unsigned short* T = &smem[0][0][0] + wave * 4608;  // [64][72] per wave
#pragma unroll
    for (int i = 0; i < 4; ++i)
#pragma unroll
      for (int f = 0; f < 4; ++f)
#pragma unroll
        for (int r = 0; r < 4; ++r) {
          int lrow = 16 * i + quad * 4 + r;   // seq-local
          int lcol = 16 * f + l15;            // dh-local
          int col = n0 + cb + 16 * f + l15;
          T[lcol * 72 + lrow] = f2bf(acc[i][f][r] + bias[col]);
        }
    const int mbase = m0 + rb;
    const int b = mbase >> 11, sbase = mbase & (SEQ - 1);
    const int head = (n0 + cb) >> 6;
    unsigned short* dstb = out + ((size_t)(b * NH + head) * DH) * SEQ + sbase;
#pragma unroll
    for (int j = 0; j < 8; ++j) {
      int dh = (lane >> 3) + j * 8;
      int sc = (lane & 7) * 8;
      *(uint4*)(dstb + (size_t)dh * SEQ + sc) = *(const uint4*)&T[dh * 72 + sc];
    }
  }
}

// ---------- flash attention (no-max exp2 softmax) -> concat bf16 [B,SEQ,DM] ----------
// Qp pre-scaled by QSCALE. grid (32 qtiles, 32 bh).
__global__ __launch_bounds__(256, 4) void attn_kernel(const unsigned short* __restrict__ Qp,
                                                      const unsigned short* __restrict__ Kp,
                                                      const unsigned short* __restrict__ Vpt,
                                                      unsigned short* __restrict__ concat) {
  const int qt = blockIdx.x;
  const int bh = blockIdx.y;
  const int b = bh >> 3, h = bh & 7;
  __shared__ __align__(16) unsigned short Ks[64][72], Vts[64][72], Ps[64][72];
  const int tid  = threadIdx.x;
  const int wave = tid >> 6, lane = tid & 63;
  const int l15  = lane & 15, quad = lane >> 4;
  const unsigned short* Qb = Qp  + (size_t)bh * SEQ * DH;
  const unsigned short* Kb = Kp  + (size_t)bh * SEQ * DH;
  const unsigned short* Vb = Vpt + (size_t)bh * DH * SEQ;
  const int q0 = qt * 64;

  // Q fragments straight to registers (rows 16w+l15, fixed per block)
  bf16x8 aq[2];
#pragma unroll
  for (int kc = 0; kc < 2; ++kc)
    aq[kc] = *(const bf16x8*)(Qb + (size_t)(q0 + 16 * wave + l15) * DH + kc * 32 + quad * 8);

  float l_lane[4];
  f32x4 Of[4];
#pragma unroll
  for (int r = 0; r < 4; ++r) l_lane[r] = 0.f;
#pragma unroll
  for (int f = 0; f < 4; ++f) Of[f] = (f32x4){0.f, 0.f, 0.f, 0.f};

#pragma unroll 1
  for (int lt = 0; lt <= qt; ++lt) {
    const int l0 = lt * 64;
    __syncthreads();
#pragma unroll
    for (int i = 0; i < 2; ++i) {
      int c = tid + 256 * i;
      int lr = c >> 3, lc = (c & 7) * 8;
      *(uint4*)&Ks[lr][lc]  = *(const uint4*)(Kb + (size_t)(l0 + lr) * DH + lc);
      *(uint4*)&Vts[lr][lc] = *(const uint4*)(Vb + (size_t)lr * SEQ + l0 + lc);
    }
    __syncthreads();

    // S' = (Q*QSCALE) K^T  (already includes log2e)
    f32x4 S[4];
#pragma unroll
    for (int f = 0; f < 4; ++f) S[f] = (f32x4){0.f, 0.f, 0.f, 0.f};
#pragma unroll
    for (int kc = 0; kc < 2; ++kc)
#pragma unroll
      for (int f = 0; f < 4; ++f) {
        bf16x8 bk = *(const bf16x8*)&Ks[16 * f + l15][kc * 32 + quad * 8];
        S[f] = __builtin_amdgcn_mfma_f32_16x16x32_bf16(aq[kc], bk, S[f], 0, 0, 0);
      }
    if (lt == qt) {
      const int mrow = q0 + 16 * wave + quad * 4;
#pragma unroll
      for (int f = 0; f < 4; ++f)
#pragma unroll
        for (int r = 0; r < 4; ++r)
          if (l0 + 16 * f + l15 > mrow + r) S[f][r] = -1e30f;
    }
    // p = exp2(S'), accumulate per-lane row partial sums (reduced once at end)
#pragma unroll
    for (int f = 0; f < 4; ++f)
#pragma unroll
      for (int r = 0; r < 4; ++r) {
        float p = __builtin_amdgcn_exp2f(S[f][r]);
        l_lane[r] += p;
        Ps[16 * wave + quad * 4 + r][16 * f + l15] = f2bf(p);  // wave-private rows
      }
    // O += P @ V
#pragma unroll
    for (int kc = 0; kc < 2; ++kc) {
      bf16x8 ap = *(const bf16x8*)&Ps[16 * wave + l15][kc * 32 + quad * 8];
#pragma unroll
      for (int f = 0; f < 4; ++f) {
        bf16x8 bv = *(const bf16x8*)&Vts[16 * f + l15][kc * 32 + quad * 8];
        Of[f] = __builtin_amdgcn_mfma_f32_16x16x32_bf16(ap, bv, Of[f], 0, 0, 0);
      }
    }
  }

  // single row-sum reduction across the 16 lanes sharing each row
#pragma unroll
  for (int d = 1; d < 16; d <<= 1)
#pragma unroll
    for (int r = 0; r < 4; ++r) l_lane[r] += __shfl_xor(l_lane[r], d);

#pragma unroll
  for (int f = 0; f < 4; ++f)
#pragma unroll
    for (int r = 0; r < 4; ++r) {
      int row = q0 + 16 * wave + quad * 4 + r;
      float o = Of[f][r] / l_lane[r];
      int col = h * DH + 16 * f + l15;
      concat[(size_t)(b * SEQ + row) * DM + col] = f2bf(o);
    }
}

// ---------- output projection: out_f32 = concat_bf16 @ Wot^T + b_o ----------
__global__ __launch_bounds__(256) void gemm_out(const unsigned short* __restrict__ A,
                                                const unsigned short* __restrict__ Bt,
                                                const float* __restrict__ bias,
                                                float* __restrict__ out) {
  const int m0 = blockIdx.x * 64;
  const int nbase = blockIdx.y * 256;
  __shared__ __align__(16) unsigned short Bs[64][72];
  const int tid  = threadIdx.x;
  const int wave = tid >> 6, lane = tid & 63;
  const int l15  = lane & 15, quad = lane >> 4;

  bf16x8 afr[16];  // per-wave A rows held in registers across all n0 tiles
  const unsigned short* arow = A + (size_t)(m0 + 16 * wave + l15) * DM;
#pragma unroll
  for (int k0i = 0; k0i < 8; ++k0i)
#pragma unroll
    for (int kc = 0; kc < 2; ++kc)
      afr[k0i * 2 + kc] = *(const bf16x8*)(arow + k0i * 64 + kc * 32 + quad * 8);

  for (int n0 = nbase; n0 < nbase + 256; n0 += 64) {
    f32x4 acc[4];
#pragma unroll
    for (int f = 0; f < 4; ++f) acc[f] = (f32x4){0.f, 0.f, 0.f, 0.f};
    for (int k0i = 0; k0i < 8; ++k0i) {
      __syncthreads();
#pragma unroll
      for (int i = 0; i < 2; ++i) {
        int c = tid + 256 * i;
        int lr = c >> 3, lc = (c & 7) * 8;
        *(uint4*)&Bs[lr][lc] = *(const uint4*)(Bt + (size_t)(n0 + lr) * DM + k0i * 64 + lc);
      }
      __syncthreads();
#pragma unroll
      for (int kc = 0; kc < 2; ++kc)
#pragma unroll
        for (int f = 0; f < 4; ++f) {
          bf16x8 bfv = *(const bf16x8*)&Bs[16 * f + l15][kc * 32 + quad * 8];
          acc[f] = __builtin_amdgcn_mfma_f32_16x16x32_bf16(afr[k0i * 2 + kc], bfv, acc[f], 0, 0, 0);
        }
    }
#pragma unroll
    for (int f = 0; f < 4; ++f)
#pragma unroll
      for (int r = 0; r < 4; ++r) {
        int row = 16 * wave + quad * 4 + r;
        int col = 16 * f + l15;
        out[(size_t)(m0 + row) * DM + n0 + col] = acc[f][r] + bias[n0 + col];
      }
  }
}

extern "C" void kernel_launch(void* const* d_in, const int* in_sizes, int n_in,
                              void* d_out, int out_size, void* d_ws, size_t ws_size,
                              hipStream_t stream) {
  const float* query = (const float*)d_in[0];
  const float* key   = (const float*)d_in[1];
  const float* value = (const float*)d_in[2];
  const float* W_q   = (const float*)d_in[3];
  const float* b_q   = (const float*)d_in[4];
  const float* W_k   = (const float*)d_in[5];
  const float* b_k   = (const float*)d_in[6];
  const float* W_v   = (const float*)d_in[7];
  const float* b_v   = (const float*)d_in[8];
  const float* W_o   = (const float*)d_in[9];
  const float* b_o   = (const float*)d_in[10];
  float* out = (float*)d_out;

  char* ws = (char*)d_ws;
  unsigned short* Wqt    = (unsigned short*)(ws + 0);         // [H][64][512] bf16
  unsigned short* Wkt    = (unsigned short*)(ws + 524288);
  unsigned short* Wvt    = (unsigned short*)(ws + 1048576);
  unsigned short* Wot    = (unsigned short*)(ws + 1572864);   // [512][512] bf16
  unsigned short* Qp     = (unsigned short*)(ws + 2097152);   // [B,H,S,64] bf16 8 MB
  unsigned short* Kp     = (unsigned short*)(ws + 10485760);
  unsigned short* Vpt    = (unsigned short*)(ws + 18874368);  // [B,H,64,S] bf16 8 MB
  unsigned short* concat = (unsigned short*)(ws + 27262976);  // [B,S,512] bf16 8 MB

  weight_prep<<<dim3(256), 256, 0, stream>>>(W_q, W_k, W_v, W_o, Wqt, Wkt, Wvt, Wot);

  proj128<<<dim3(64, 4, 3), 256, 0, stream>>>(query, key, value, Wqt, Wkt, Wvt,
                                              b_q, b_k, b_v, Qp, Kp, Vpt);

  attn_kernel<<<dim3(32, 32), 256, 0, stream>>>(Qp, Kp, Vpt, concat);

  gemm_out<<<dim3(128, 2), 256, 0, stream>>>(concat, Wot, b_o, out);
}